// Round 15
// baseline (333.744 us; speedup 1.0000x reference)
//
#include <hip/hip_runtime.h>

#define HW 28
#define NPIX 784
#define NB 512
#define PADW2 34                 // row stride in float2 (cols -3..30) = 272 B (16B mult)
#define PADH 34                  // rows -3..30
#define IMG_F2 (PADH * PADW2)    // 1156 float2 = 9248 B

typedef float v2f __attribute__((ext_vector_type(2)));

// ---------------------------------------------------------------------------
// 7x2 output tile per thread, TWO-PASS over kernel rows so the live weight
// block fits the 128-VGPR allocation with no in-loop remat (r13 limiter:
// W[49]=98 regs + 42 acc + 16 taps > 128 -> compiler rematerialized W from
// LDS inside the loop, lgkm-serializing the FMA stream; VALUBusy pinned 36%).
//   pass A: weight rows 0..3 (56 regs), tap rows R0..R0+9
//   pass B: weight rows 4..6 (42 regs), tap rows R0+4..R0+12
// Peak live ~114. Cost: 19 tap-row reads vs 13 (+46% LDS, within headroom).
// W = (qw, ew) = (w*e^{aw}, e^{aw}); out = sum((ev,pv).(qw,ew)) / sum(ev*ew)
// ---------------------------------------------------------------------------
__device__ __forceinline__ void conv2col(const float2* sbuf,
                                         const float2* wlds,   // LDS, 16B-aligned
                                         int R0, int c, float o0[7], float o1[7])
{
    v2f   sN0[7], sN1[7];
    float sD0[7], sD1[7];
#pragma unroll
    for (int r = 0; r < 7; ++r) {
        sN0[r] = (v2f){0.f, 0.f}; sN1[r] = (v2f){0.f, 0.f};
        sD0[r] = 0.f; sD1[r] = 0.f;
    }

    // ---- pass A: kernel rows di = 0..3 ----
    {
        v2f WA[28];
        const float4* wp = (const float4*)wlds;    // broadcast, conflict-free
#pragma unroll
        for (int k = 0; k < 14; ++k) {
            float4 q = wp[k];
            WA[2 * k]     = (v2f){q.x, q.y};
            WA[2 * k + 1] = (v2f){q.z, q.w};
        }
#pragma unroll
        for (int rr = 0; rr < 10; ++rr) {
            const float4* rq = (const float4*)(sbuf + (R0 + rr) * PADW2 + 2 * c);
            float4 q0 = rq[0], q1 = rq[1], q2 = rq[2], q3 = rq[3];
            v2f tp[8] = {{q0.x, q0.y}, {q0.z, q0.w}, {q1.x, q1.y}, {q1.z, q1.w},
                         {q2.x, q2.y}, {q2.z, q2.w}, {q3.x, q3.y}, {q3.z, q3.w}};
#pragma unroll
            for (int dl = 0; dl < 4; ++dl) {
                const int r = rr - dl;
                if (r < 0 || r > 6) continue;       // compile-time fold
#pragma unroll
                for (int t = 0; t < 7; ++t) {
                    v2f wq = WA[dl * 7 + t];        // (qw, ew)
                    sN0[r] = __builtin_elementwise_fma(tp[t],     wq, sN0[r]);
                    sN1[r] = __builtin_elementwise_fma(tp[t + 1], wq, sN1[r]);
                    sD0[r] = fmaf(tp[t][0],     wq[1], sD0[r]);
                    sD1[r] = fmaf(tp[t + 1][0], wq[1], sD1[r]);
                }
            }
        }
    }

    // ---- pass B: kernel rows di = 4..6 ----
    {
        v2f WB[21];
        const float4* wp = (const float4*)(wlds + 28);   // 224 B offset, aligned
#pragma unroll
        for (int k = 0; k < 10; ++k) {
            float4 q = wp[k];
            WB[2 * k]     = (v2f){q.x, q.y};
            WB[2 * k + 1] = (v2f){q.z, q.w};
        }
        float2 lastw = wlds[48];
        WB[20] = (v2f){lastw.x, lastw.y};
#pragma unroll
        for (int k = 0; k < 9; ++k) {               // tap row rr = k + 4
            const float4* rq = (const float4*)(sbuf + (R0 + k + 4) * PADW2 + 2 * c);
            float4 q0 = rq[0], q1 = rq[1], q2 = rq[2], q3 = rq[3];
            v2f tp[8] = {{q0.x, q0.y}, {q0.z, q0.w}, {q1.x, q1.y}, {q1.z, q1.w},
                         {q2.x, q2.y}, {q2.z, q2.w}, {q3.x, q3.y}, {q3.z, q3.w}};
#pragma unroll
            for (int dl = 0; dl < 3; ++dl) {        // di = dl + 4
                const int r = k - dl;
                if (r < 0 || r > 6) continue;       // compile-time fold
#pragma unroll
                for (int t = 0; t < 7; ++t) {
                    v2f wq = WB[dl * 7 + t];
                    sN0[r] = __builtin_elementwise_fma(tp[t],     wq, sN0[r]);
                    sN1[r] = __builtin_elementwise_fma(tp[t + 1], wq, sN1[r]);
                    sD0[r] = fmaf(tp[t][0],     wq[1], sD0[r]);
                    sD1[r] = fmaf(tp[t + 1][0], wq[1], sD1[r]);
                }
            }
        }
    }

#pragma unroll
    for (int r = 0; r < 7; ++r) {
        o0[r] = (sN0[r][0] + sN0[r][1]) * __builtin_amdgcn_rcpf(sD0[r]);
        o1[r] = (sN1[r][0] + sN1[r][1]) * __builtin_amdgcn_rcpf(sD1[r]);
    }
}

__device__ __forceinline__ float sigmoidf_(float s) {
    return __builtin_amdgcn_rcpf(1.f + __expf(-s));
}

// ---------------------------------------------------------------------------
// FULLY FUSED, 8 waves/block, ONE BRANCH PER WAVE, one block per image
// (r13 structure). LDS 80,384 B -> 2 blocks/CU = 16 waves/CU = 4 waves/SIMD.
// __launch_bounds__(512,2): 2nd arg is min BLOCKS per CU (r12 lesson:
// (512,4) forced VGPR cap 64 -> 2.7 GB scratch traffic). (512,2) -> cap 128.
// ---------------------------------------------------------------------------
__global__ __launch_bounds__(512, 2) void smorph_net_kernel(
    const float* __restrict__ x,       // [512,784]
    const float* __restrict__ sw,      // [8,2,49]
    const float* __restrict__ sa,      // [8,2]
    const float* __restrict__ W1, const float* __restrict__ b1,
    const float* __restrict__ W2, const float* __restrict__ b2,
    const float* __restrict__ W3, const float* __restrict__ b3,
    float* __restrict__ out)           // [512,10]
{
    __shared__ __align__(16) float2 bufs[8][IMG_F2];   // 73,984 B
    __shared__ __align__(16) float2 wtab[8][2][50];    //  6,400 B (50 -> both stages 16B-aligned)

    const int b    = blockIdx.x;       // 512 blocks
    const int tid  = threadIdx.x;      // 0..511
    const int f    = tid >> 6;         // wave = branch
    const int lane = tid & 63;

    float2* buf = bufs[f];
    const float* src = x + (size_t)b * NPIX;

    const float a1 = sa[f * 2 + 0];
    const float a2 = sa[f * 2 + 1];

    // per-branch weight tables (wave-local writes; program order protects)
    if (lane < 49) {
        float w1v = sw[(f * 2 + 0) * 49 + lane];
        float e1  = __expf(a1 * w1v);
        wtab[f][0][lane] = make_float2(w1v * e1, e1);
        float w2v = sw[(f * 2 + 1) * 49 + lane];
        float e2  = __expf(a2 * w2v);
        wtab[f][1][lane] = make_float2(w2v * e2, e2);
    }

    // phase 0: buf = padded (ev,pv); borders (1,0)  (SAME zero-pad)
    for (int idx = lane; idx < IMG_F2; idx += 64) {
        int pi = idx / PADW2;
        int pj = idx - pi * PADW2;
        float2 val = make_float2(1.f, 0.f);
        if (pi >= 3 && pi < 31 && pj >= 3 && pj < 31) {
            float v = src[(pi - 3) * HW + (pj - 3)];
            float e = __expf(a1 * v);
            val = make_float2(e, v * e);
        }
        buf[idx] = val;
    }

    const bool act = (lane < 56);
    const int s  = lane / 14;          // strip (output rows 7s..7s+6)
    const int c  = lane - s * 14;      // column pair 0..13
    const int R0 = 7 * s;
    const int j2 = 2 * c;

    float o0[7], o1[7];
    if (act) conv2col(buf, wtab[f][0], R0, c, o0, o1);

    // stage-2 (ev,pv) overwrite interior in place (own-wave conv1 reads done)
    if (act) {
#pragma unroll
        for (int r = 0; r < 7; ++r) {
            float e0 = __expf(a2 * o0[r]);
            float e1 = __expf(a2 * o1[r]);
            buf[(R0 + r + 3) * PADW2 + (j2 + 3)] = make_float2(e0, o0[r] * e0);
            buf[(R0 + r + 3) * PADW2 + (j2 + 4)] = make_float2(e1, o1[r] * e1);
        }
    }

    if (act) conv2col(buf, wtab[f][1], R0, c, o0, o1);

    // dense 28x28 plane aliased over own buf
    float* outp = (float*)buf;
    if (act) {
#pragma unroll
        for (int r = 0; r < 7; ++r) {
            outp[(R0 + r) * HW + j2]     = o0[r];
            outp[(R0 + r) * HW + j2 + 1] = o1[r];
        }
    }

    // 4x4 mean pool -> REGISTER (feat write must wait: it aliases wtab)
    float poolsum = 0.f;
    if (lane < 49) {
        int pi = lane / 7;
        int pj = lane - pi * 7;
#pragma unroll
        for (int di = 0; di < 4; ++di)
#pragma unroll
            for (int dj = 0; dj < 4; ++dj)
                poolsum += outp[(pi * 4 + di) * HW + (pj * 4 + dj)];
        poolsum *= 0.0625f;
    }
    __syncthreads();                    // all convs done; wtab now dead

    // feat/h1/h2 alias the wtab region (2,384 B needed, 6,400 available)
    float* feat = (float*)&wtab[0][0][0];
    float* h1   = feat + 392;           // offset 1568 B (16B mult)
    float* h2   = h1 + 120;             // offset 2048 B (16B mult)

    if (lane < 49) feat[f * 49 + lane] = poolsum;
    __syncthreads();

    // ---- inline MLP ----
    if (tid < 240) {
        int n = tid >> 1, h = tid & 1;
        const float4* wr = (const float4*)(W1 + n * 392);
        const float4* fv = (const float4*)feat;
        float c0 = 0.f, c1 = 0.f, c2 = 0.f, c3 = 0.f;
#pragma unroll 7
        for (int k = h; k < 98; k += 2) {
            float4 w = wr[k];
            float4 v = fv[k];
            c0 = fmaf(w.x, v.x, c0);
            c1 = fmaf(w.y, v.y, c1);
            c2 = fmaf(w.z, v.z, c2);
            c3 = fmaf(w.w, v.w, c3);
        }
        float acc = (c0 + c1) + (c2 + c3);
        acc += __shfl_xor(acc, 1);
        if (h == 0) h1[n] = sigmoidf_(acc + b1[n]);
    }
    __syncthreads();

    if (tid < 168) {
        int n = tid >> 1, h = tid & 1;
        const float4* wr = (const float4*)(W2 + n * 120);
        const float4* hv = (const float4*)h1;
        float c0 = 0.f, c1 = 0.f, c2 = 0.f, c3 = 0.f;
#pragma unroll
        for (int k = h; k < 30; k += 2) {
            float4 w = wr[k];
            float4 v = hv[k];
            c0 = fmaf(w.x, v.x, c0);
            c1 = fmaf(w.y, v.y, c1);
            c2 = fmaf(w.z, v.z, c2);
            c3 = fmaf(w.w, v.w, c3);
        }
        float acc = (c0 + c1) + (c2 + c3);
        acc += __shfl_xor(acc, 1);
        if (h == 0) h2[n] = sigmoidf_(acc + b2[n]);
    }
    __syncthreads();

    if (tid < 40) {
        int n = tid >> 2, q = tid & 3;
        const float4* wr = (const float4*)(W3 + n * 84);
        const float4* hv = (const float4*)h2;
        float c0 = 0.f, c1 = 0.f, c2 = 0.f, c3 = 0.f;
        for (int k = q; k < 21; k += 4) {
            float4 w = wr[k];
            float4 v = hv[k];
            c0 = fmaf(w.x, v.x, c0);
            c1 = fmaf(w.y, v.y, c1);
            c2 = fmaf(w.z, v.z, c2);
            c3 = fmaf(w.w, v.w, c3);
        }
        float acc = (c0 + c1) + (c2 + c3);
        acc += __shfl_xor(acc, 1);
        acc += __shfl_xor(acc, 2);
        if (q == 0) out[(size_t)b * 10 + n] = sigmoidf_(acc + b3[n]);
    }
}

extern "C" void kernel_launch(void* const* d_in, const int* in_sizes, int n_in,
                              void* d_out, int out_size, void* d_ws, size_t ws_size,
                              hipStream_t stream) {
    const float* x  = (const float*)d_in[0];
    const float* sw = (const float*)d_in[1];
    const float* sa = (const float*)d_in[2];
    const float* W1 = (const float*)d_in[3];
    const float* b1 = (const float*)d_in[4];
    const float* W2 = (const float*)d_in[5];
    const float* b2 = (const float*)d_in[6];
    const float* W3 = (const float*)d_in[7];
    const float* b3 = (const float*)d_in[8];
    float* out = (float*)d_out;

    smorph_net_kernel<<<NB, 512, 0, stream>>>(x, sw, sa, W1, b1, W2, b2, W3, b3, out);
}

// Round 16
// 222.550 us; speedup vs baseline: 1.4996x; 1.4996x over previous
//
#include <hip/hip_runtime.h>

#define HW 28
#define NPIX 784
#define NB 512
#define PADW2 34                 // row stride in float2 (cols -3..30) = 272 B (16B mult)
#define PADH 34                  // rows -3..30
#define IMG_F2 (PADH * PADW2)    // 1156 float2 = 9248 B

// force a wave-uniform float into an SGPR (VALU op, no memory, no lgkm)
__device__ __forceinline__ float rfl(float v) {
    return __builtin_bit_cast(float, __builtin_amdgcn_readfirstlane(__builtin_bit_cast(int, v)));
}

// ---------------------------------------------------------------------------
// 7x2 output tile per thread. Factored SMorph tap:
//   num += ew*(w*ev + pv);  den += ew*ev;   out = num/den
// w[49] lives in VGPRs (49), ew[49] lives in SGPRs (readfirstlane-forced) —
// each fma reads at most 1 SGPR (ISA-legal). Accumulators 28 (num,den x14).
// Steady live ~105 VGPR < 128 cap: no remat (r13's limiter), no spill
// (r14/r15's failure). 3 fma per tap-output.
// ---------------------------------------------------------------------------
__device__ __forceinline__ void conv2col(const float2* sbuf,
                                         const float* wlds,    // LDS w[49], 16B-aligned
                                         const float* elds,    // LDS ew[49], 16B-aligned
                                         int R0, int c, float o0[7], float o1[7])
{
    // ew -> SGPRs (transient VGPRs freed immediately)
    float ews[49];
    {
        const float4* ep = (const float4*)elds;
#pragma unroll
        for (int k = 0; k < 12; ++k) {
            float4 q = ep[k];
            ews[4 * k + 0] = rfl(q.x); ews[4 * k + 1] = rfl(q.y);
            ews[4 * k + 2] = rfl(q.z); ews[4 * k + 3] = rfl(q.w);
        }
        ews[48] = rfl(elds[48]);
    }
    // w -> VGPRs
    float Wv[49];
    {
        const float4* wp = (const float4*)wlds;
#pragma unroll
        for (int k = 0; k < 12; ++k) {
            float4 q = wp[k];
            Wv[4 * k + 0] = q.x; Wv[4 * k + 1] = q.y;
            Wv[4 * k + 2] = q.z; Wv[4 * k + 3] = q.w;
        }
        Wv[48] = wlds[48];
    }

    float num0[7], num1[7], den0[7], den1[7];
#pragma unroll
    for (int r = 0; r < 7; ++r) {
        num0[r] = 0.f; num1[r] = 0.f; den0[r] = 0.f; den1[r] = 0.f;
    }

#pragma unroll
    for (int rr = 0; rr < 13; ++rr) {
        const float4* rq = (const float4*)(sbuf + (R0 + rr) * PADW2 + 2 * c);
        float4 q0 = rq[0], q1 = rq[1], q2 = rq[2], q3 = rq[3];
        float ev[8] = {q0.x, q0.z, q1.x, q1.z, q2.x, q2.z, q3.x, q3.z};
        float pv[8] = {q0.y, q0.w, q1.y, q1.w, q2.y, q2.w, q3.y, q3.w};
#pragma unroll
        for (int r = 0; r < 7; ++r) {
            if (r > rr || rr - r > 6) continue;     // compile-time fold
            const int di = rr - r;
#pragma unroll
            for (int t = 0; t < 7; ++t) {
                float w  = Wv[di * 7 + t];          // VGPR
                float ew = ews[di * 7 + t];         // SGPR
                float t1a = fmaf(w, ev[t],     pv[t]);
                float t1b = fmaf(w, ev[t + 1], pv[t + 1]);
                num0[r] = fmaf(ew, t1a, num0[r]);
                num1[r] = fmaf(ew, t1b, num1[r]);
                den0[r] = fmaf(ew, ev[t],     den0[r]);
                den1[r] = fmaf(ew, ev[t + 1], den1[r]);
            }
        }
    }
#pragma unroll
    for (int r = 0; r < 7; ++r) {
        o0[r] = num0[r] * __builtin_amdgcn_rcpf(den0[r]);
        o1[r] = num1[r] * __builtin_amdgcn_rcpf(den1[r]);
    }
}

__device__ __forceinline__ float sigmoidf_(float s) {
    return __builtin_amdgcn_rcpf(1.f + __expf(-s));
}

// ---------------------------------------------------------------------------
// FULLY FUSED, 8 waves/block, ONE BRANCH PER WAVE, one block per image
// (r13 structure). LDS 80,640 B -> 2 blocks/CU = 16 waves/CU = 4 waves/SIMD.
// __launch_bounds__(512,2): 2nd arg is min BLOCKS per CU (r12 lesson:
// (512,4) forced VGPR cap 64 -> 2.7 GB scratch traffic). (512,2) -> cap 128.
// ---------------------------------------------------------------------------
__global__ __launch_bounds__(512, 2) void smorph_net_kernel(
    const float* __restrict__ x,       // [512,784]
    const float* __restrict__ sw,      // [8,2,49]
    const float* __restrict__ sa,      // [8,2]
    const float* __restrict__ W1, const float* __restrict__ b1,
    const float* __restrict__ W2, const float* __restrict__ b2,
    const float* __restrict__ W3, const float* __restrict__ b3,
    float* __restrict__ out)           // [512,10]
{
    __shared__ __align__(16) float2 bufs[8][IMG_F2];   // 73,984 B
    __shared__ __align__(16) float  wlds[8][2][52];    //  3,328 B (w values)
    __shared__ __align__(16) float  elds[8][2][52];    //  3,328 B (ew values)

    const int b    = blockIdx.x;       // 512 blocks
    const int tid  = threadIdx.x;      // 0..511
    const int f    = tid >> 6;         // wave = branch
    const int lane = tid & 63;

    float2* buf = bufs[f];
    const float* src = x + (size_t)b * NPIX;

    const float a1 = sa[f * 2 + 0];
    const float a2 = sa[f * 2 + 1];

    // per-branch weight tables (wave-local writes; program order protects)
    if (lane < 49) {
        float w1v = sw[(f * 2 + 0) * 49 + lane];
        wlds[f][0][lane] = w1v;
        elds[f][0][lane] = __expf(a1 * w1v);
        float w2v = sw[(f * 2 + 1) * 49 + lane];
        wlds[f][1][lane] = w2v;
        elds[f][1][lane] = __expf(a2 * w2v);
    }

    // phase 0: buf = padded (ev,pv); borders (1,0)  (SAME zero-pad)
    for (int idx = lane; idx < IMG_F2; idx += 64) {
        int pi = idx / PADW2;
        int pj = idx - pi * PADW2;
        float2 val = make_float2(1.f, 0.f);
        if (pi >= 3 && pi < 31 && pj >= 3 && pj < 31) {
            float v = src[(pi - 3) * HW + (pj - 3)];
            float e = __expf(a1 * v);
            val = make_float2(e, v * e);
        }
        buf[idx] = val;
    }

    const bool act = (lane < 56);
    const int s  = lane / 14;          // strip (output rows 7s..7s+6)
    const int c  = lane - s * 14;      // column pair 0..13
    const int R0 = 7 * s;
    const int j2 = 2 * c;

    float o0[7], o1[7];
    if (act) conv2col(buf, wlds[f][0], elds[f][0], R0, c, o0, o1);

    // stage-2 (ev,pv) overwrite interior in place (own-wave conv1 reads done)
    if (act) {
#pragma unroll
        for (int r = 0; r < 7; ++r) {
            float e0 = __expf(a2 * o0[r]);
            float e1 = __expf(a2 * o1[r]);
            buf[(R0 + r + 3) * PADW2 + (j2 + 3)] = make_float2(e0, o0[r] * e0);
            buf[(R0 + r + 3) * PADW2 + (j2 + 4)] = make_float2(e1, o1[r] * e1);
        }
    }

    if (act) conv2col(buf, wlds[f][1], elds[f][1], R0, c, o0, o1);

    // dense 28x28 plane aliased over own buf
    float* outp = (float*)buf;
    if (act) {
#pragma unroll
        for (int r = 0; r < 7; ++r) {
            outp[(R0 + r) * HW + j2]     = o0[r];
            outp[(R0 + r) * HW + j2 + 1] = o1[r];
        }
    }

    // 4x4 mean pool -> REGISTER (feat write must wait: it aliases wlds)
    float poolsum = 0.f;
    if (lane < 49) {
        int pi = lane / 7;
        int pj = lane - pi * 7;
#pragma unroll
        for (int di = 0; di < 4; ++di)
#pragma unroll
            for (int dj = 0; dj < 4; ++dj)
                poolsum += outp[(pi * 4 + di) * HW + (pj * 4 + dj)];
        poolsum *= 0.0625f;
    }
    __syncthreads();                    // all convs done; wlds/elds now dead

    // feat/h1/h2 alias the weight-table region (2,384 B needed, 6,656 avail)
    float* feat = &wlds[0][0][0];
    float* h1   = feat + 392;           // offset 1568 B (16B mult)
    float* h2   = h1 + 120;             // offset 2048 B (16B mult)

    if (lane < 49) feat[f * 49 + lane] = poolsum;
    __syncthreads();

    // ---- inline MLP ----
    if (tid < 240) {
        int n = tid >> 1, h = tid & 1;
        const float4* wr = (const float4*)(W1 + n * 392);
        const float4* fv = (const float4*)feat;
        float c0 = 0.f, c1 = 0.f, c2 = 0.f, c3 = 0.f;
#pragma unroll 7
        for (int k = h; k < 98; k += 2) {
            float4 w = wr[k];
            float4 v = fv[k];
            c0 = fmaf(w.x, v.x, c0);
            c1 = fmaf(w.y, v.y, c1);
            c2 = fmaf(w.z, v.z, c2);
            c3 = fmaf(w.w, v.w, c3);
        }
        float acc = (c0 + c1) + (c2 + c3);
        acc += __shfl_xor(acc, 1);
        if (h == 0) h1[n] = sigmoidf_(acc + b1[n]);
    }
    __syncthreads();

    if (tid < 168) {
        int n = tid >> 1, h = tid & 1;
        const float4* wr = (const float4*)(W2 + n * 120);
        const float4* hv = (const float4*)h1;
        float c0 = 0.f, c1 = 0.f, c2 = 0.f, c3 = 0.f;
#pragma unroll
        for (int k = h; k < 30; k += 2) {
            float4 w = wr[k];
            float4 v = hv[k];
            c0 = fmaf(w.x, v.x, c0);
            c1 = fmaf(w.y, v.y, c1);
            c2 = fmaf(w.z, v.z, c2);
            c3 = fmaf(w.w, v.w, c3);
        }
        float acc = (c0 + c1) + (c2 + c3);
        acc += __shfl_xor(acc, 1);
        if (h == 0) h2[n] = sigmoidf_(acc + b2[n]);
    }
    __syncthreads();

    if (tid < 40) {
        int n = tid >> 2, q = tid & 3;
        const float4* wr = (const float4*)(W3 + n * 84);
        const float4* hv = (const float4*)h2;
        float c0 = 0.f, c1 = 0.f, c2 = 0.f, c3 = 0.f;
        for (int k = q; k < 21; k += 4) {
            float4 w = wr[k];
            float4 v = hv[k];
            c0 = fmaf(w.x, v.x, c0);
            c1 = fmaf(w.y, v.y, c1);
            c2 = fmaf(w.z, v.z, c2);
            c3 = fmaf(w.w, v.w, c3);
        }
        float acc = (c0 + c1) + (c2 + c3);
        acc += __shfl_xor(acc, 1);
        acc += __shfl_xor(acc, 2);
        if (q == 0) out[(size_t)b * 10 + n] = sigmoidf_(acc + b3[n]);
    }
}

extern "C" void kernel_launch(void* const* d_in, const int* in_sizes, int n_in,
                              void* d_out, int out_size, void* d_ws, size_t ws_size,
                              hipStream_t stream) {
    const float* x  = (const float*)d_in[0];
    const float* sw = (const float*)d_in[1];
    const float* sa = (const float*)d_in[2];
    const float* W1 = (const float*)d_in[3];
    const float* b1 = (const float*)d_in[4];
    const float* W2 = (const float*)d_in[5];
    const float* b2 = (const float*)d_in[6];
    const float* W3 = (const float*)d_in[7];
    const float* b3 = (const float*)d_in[8];
    float* out = (float*)d_out;

    smorph_net_kernel<<<NB, 512, 0, stream>>>(x, sw, sa, W1, b1, W2, b2, W3, b3, out);
}

// Round 17
// 113.922 us; speedup vs baseline: 2.9296x; 1.9535x over previous
//
#include <hip/hip_runtime.h>

#define HW 28
#define NPIX 784
#define NB 512
#define PADW2 34                 // row stride in float2 (cols -3..30) = 272 B (16B mult)
#define PADH 34                  // rows -3..30
#define IMG_F2 (PADH * PADW2)    // 1156 float2 = 9248 B

// ---------------------------------------------------------------------------
// 7x2 output tile per thread. Weights packed one VGPR each: lo16 = w (f16),
// hi16 = ew = exp(a*w) (f16). Inner math is v_fma_mix_f32 via inline asm —
// the f16->f32 conversion happens INSIDE the fma (op_sel), so there is no
// conversion op for LICM to hoist (r14's failure: hoisted (float)half temps
// recreated 98 f32 regs -> spill; r15/r16 variants also spilled).
//   t1  = fma(w,  ev, pv)        num += ew * t1        den += ew * ev
//   out = num / den
// Live set: 49 W + 28 acc + 16 taps + ~10 addr ~= 103 < 128 cap.
// ---------------------------------------------------------------------------
__device__ __forceinline__ void conv2col(const float2* sbuf,
                                         const unsigned* wlds,  // LDS packed, 16B-aligned
                                         int R0, int c, float o0[7], float o1[7])
{
    unsigned Wh[49];
    {
        const uint4* wp = (const uint4*)wlds;      // broadcast, conflict-free
#pragma unroll
        for (int k = 0; k < 12; ++k) {
            uint4 q = wp[k];
            Wh[4 * k + 0] = q.x; Wh[4 * k + 1] = q.y;
            Wh[4 * k + 2] = q.z; Wh[4 * k + 3] = q.w;
        }
        Wh[48] = wlds[48];
    }

    float num0[7], num1[7], den0[7], den1[7];
#pragma unroll
    for (int r = 0; r < 7; ++r) {
        num0[r] = 0.f; num1[r] = 0.f; den0[r] = 0.f; den1[r] = 0.f;
    }

#pragma unroll
    for (int rr = 0; rr < 13; ++rr) {
        const float4* rq = (const float4*)(sbuf + (R0 + rr) * PADW2 + 2 * c);
        float4 q0 = rq[0], q1 = rq[1], q2 = rq[2], q3 = rq[3];
        float ev[8] = {q0.x, q0.z, q1.x, q1.z, q2.x, q2.z, q3.x, q3.z};
        float pv[8] = {q0.y, q0.w, q1.y, q1.w, q2.y, q2.w, q3.y, q3.w};
#pragma unroll
        for (int r = 0; r < 7; ++r) {
            if (r > rr || rr - r > 6) continue;     // compile-time fold
            const int di = rr - r;
#pragma unroll
            for (int t = 0; t < 7; ++t) {
                unsigned w = Wh[di * 7 + t];
                float t1a, t1b;
                // t1 = f32(lo16(w)) * ev + pv
                asm("v_fma_mix_f32 %0, %1, %2, %3 op_sel_hi:[1,0,0]"
                    : "=v"(t1a) : "v"(w), "v"(ev[t]),     "v"(pv[t]));
                asm("v_fma_mix_f32 %0, %1, %2, %3 op_sel_hi:[1,0,0]"
                    : "=v"(t1b) : "v"(w), "v"(ev[t + 1]), "v"(pv[t + 1]));
                // num += f32(hi16(w)) * t1
                asm("v_fma_mix_f32 %0, %1, %2, %0 op_sel:[1,0,0] op_sel_hi:[1,0,0]"
                    : "+v"(num0[r]) : "v"(w), "v"(t1a));
                asm("v_fma_mix_f32 %0, %1, %2, %0 op_sel:[1,0,0] op_sel_hi:[1,0,0]"
                    : "+v"(num1[r]) : "v"(w), "v"(t1b));
                // den += f32(hi16(w)) * ev
                asm("v_fma_mix_f32 %0, %1, %2, %0 op_sel:[1,0,0] op_sel_hi:[1,0,0]"
                    : "+v"(den0[r]) : "v"(w), "v"(ev[t]));
                asm("v_fma_mix_f32 %0, %1, %2, %0 op_sel:[1,0,0] op_sel_hi:[1,0,0]"
                    : "+v"(den1[r]) : "v"(w), "v"(ev[t + 1]));
            }
        }
    }
#pragma unroll
    for (int r = 0; r < 7; ++r) {
        o0[r] = num0[r] * __builtin_amdgcn_rcpf(den0[r]);
        o1[r] = num1[r] * __builtin_amdgcn_rcpf(den1[r]);
    }
}

__device__ __forceinline__ float sigmoidf_(float s) {
    return __builtin_amdgcn_rcpf(1.f + __expf(-s));
}

// ---------------------------------------------------------------------------
// FULLY FUSED, 8 waves/block, ONE BRANCH PER WAVE, one block per image
// (r13 structure). LDS 77,312 B -> 2 blocks/CU = 16 waves/CU = 4 waves/SIMD.
// __launch_bounds__(512,2): 2nd arg is min BLOCKS per CU (r12 lesson:
// (512,4) forced VGPR cap 64 -> 2.7 GB scratch traffic). (512,2) -> cap 128.
// ---------------------------------------------------------------------------
__global__ __launch_bounds__(512, 2) void smorph_net_kernel(
    const float* __restrict__ x,       // [512,784]
    const float* __restrict__ sw,      // [8,2,49]
    const float* __restrict__ sa,      // [8,2]
    const float* __restrict__ W1, const float* __restrict__ b1,
    const float* __restrict__ W2, const float* __restrict__ b2,
    const float* __restrict__ W3, const float* __restrict__ b3,
    float* __restrict__ out)           // [512,10]
{
    __shared__ __align__(16) float2   bufs[8][IMG_F2];   // 73,984 B
    __shared__ __align__(16) unsigned wtab[8][2][52];    //  3,328 B

    const int b    = blockIdx.x;       // 512 blocks
    const int tid  = threadIdx.x;      // 0..511
    const int f    = tid >> 6;         // wave = branch
    const int lane = tid & 63;

    float2* buf = bufs[f];
    const float* src = x + (size_t)b * NPIX;

    const float a1 = sa[f * 2 + 0];
    const float a2 = sa[f * 2 + 1];

    // per-branch packed weight tables (wave-local; program order protects)
    if (lane < 49) {
        union { _Float16 h[2]; unsigned u; } p;
        float w1v = sw[(f * 2 + 0) * 49 + lane];
        p.h[0] = (_Float16)w1v;                 // lo = w
        p.h[1] = (_Float16)__expf(a1 * w1v);    // hi = ew
        wtab[f][0][lane] = p.u;
        float w2v = sw[(f * 2 + 1) * 49 + lane];
        p.h[0] = (_Float16)w2v;
        p.h[1] = (_Float16)__expf(a2 * w2v);
        wtab[f][1][lane] = p.u;
    }

    // phase 0: buf = padded (ev,pv); borders (1,0)  (SAME zero-pad)
    for (int idx = lane; idx < IMG_F2; idx += 64) {
        int pi = idx / PADW2;
        int pj = idx - pi * PADW2;
        float2 val = make_float2(1.f, 0.f);
        if (pi >= 3 && pi < 31 && pj >= 3 && pj < 31) {
            float v = src[(pi - 3) * HW + (pj - 3)];
            float e = __expf(a1 * v);
            val = make_float2(e, v * e);
        }
        buf[idx] = val;
    }

    const bool act = (lane < 56);
    const int s  = lane / 14;          // strip (output rows 7s..7s+6)
    const int c  = lane - s * 14;      // column pair 0..13
    const int R0 = 7 * s;
    const int j2 = 2 * c;

    float o0[7], o1[7];
    if (act) conv2col(buf, wtab[f][0], R0, c, o0, o1);

    // stage-2 (ev,pv) overwrite interior in place (own-wave conv1 reads done)
    if (act) {
#pragma unroll
        for (int r = 0; r < 7; ++r) {
            float e0 = __expf(a2 * o0[r]);
            float e1 = __expf(a2 * o1[r]);
            buf[(R0 + r + 3) * PADW2 + (j2 + 3)] = make_float2(e0, o0[r] * e0);
            buf[(R0 + r + 3) * PADW2 + (j2 + 4)] = make_float2(e1, o1[r] * e1);
        }
    }

    if (act) conv2col(buf, wtab[f][1], R0, c, o0, o1);

    // dense 28x28 plane aliased over own buf
    float* outp = (float*)buf;
    if (act) {
#pragma unroll
        for (int r = 0; r < 7; ++r) {
            outp[(R0 + r) * HW + j2]     = o0[r];
            outp[(R0 + r) * HW + j2 + 1] = o1[r];
        }
    }

    // 4x4 mean pool -> REGISTER (feat write must wait: it aliases wtab)
    float poolsum = 0.f;
    if (lane < 49) {
        int pi = lane / 7;
        int pj = lane - pi * 7;
#pragma unroll
        for (int di = 0; di < 4; ++di)
#pragma unroll
            for (int dj = 0; dj < 4; ++dj)
                poolsum += outp[(pi * 4 + di) * HW + (pj * 4 + dj)];
        poolsum *= 0.0625f;
    }
    __syncthreads();                    // all convs done; wtab now dead

    // feat/h1/h2 alias the wtab region (2,384 B needed, 3,328 available)
    float* feat = (float*)&wtab[0][0][0];
    float* h1   = feat + 392;           // offset 1568 B (16B mult)
    float* h2   = h1 + 120;             // offset 2048 B (16B mult)

    if (lane < 49) feat[f * 49 + lane] = poolsum;
    __syncthreads();

    // ---- inline MLP (L1/L2 widened to 4 lanes per neuron) ----
    if (tid < 480) {
        int n = tid >> 2, h = tid & 3;
        const float4* wr = (const float4*)(W1 + n * 392);
        const float4* fv = (const float4*)feat;
        float c0 = 0.f, c1 = 0.f, c2 = 0.f, c3 = 0.f;
        for (int k = h; k < 98; k += 4) {
            float4 w = wr[k];
            float4 v = fv[k];
            c0 = fmaf(w.x, v.x, c0);
            c1 = fmaf(w.y, v.y, c1);
            c2 = fmaf(w.z, v.z, c2);
            c3 = fmaf(w.w, v.w, c3);
        }
        float acc = (c0 + c1) + (c2 + c3);
        acc += __shfl_xor(acc, 1);
        acc += __shfl_xor(acc, 2);
        if (h == 0) h1[n] = sigmoidf_(acc + b1[n]);
    }
    __syncthreads();

    if (tid < 336) {
        int n = tid >> 2, h = tid & 3;
        const float4* wr = (const float4*)(W2 + n * 120);
        const float4* hv = (const float4*)h1;
        float c0 = 0.f, c1 = 0.f, c2 = 0.f, c3 = 0.f;
        for (int k = h; k < 30; k += 4) {
            float4 w = wr[k];
            float4 v = hv[k];
            c0 = fmaf(w.x, v.x, c0);
            c1 = fmaf(w.y, v.y, c1);
            c2 = fmaf(w.z, v.z, c2);
            c3 = fmaf(w.w, v.w, c3);
        }
        float acc = (c0 + c1) + (c2 + c3);
        acc += __shfl_xor(acc, 1);
        acc += __shfl_xor(acc, 2);
        if (h == 0) h2[n] = sigmoidf_(acc + b2[n]);
    }
    __syncthreads();

    if (tid < 40) {
        int n = tid >> 2, q = tid & 3;
        const float4* wr = (const float4*)(W3 + n * 84);
        const float4* hv = (const float4*)h2;
        float c0 = 0.f, c1 = 0.f, c2 = 0.f, c3 = 0.f;
        for (int k = q; k < 21; k += 4) {
            float4 w = wr[k];
            float4 v = hv[k];
            c0 = fmaf(w.x, v.x, c0);
            c1 = fmaf(w.y, v.y, c1);
            c2 = fmaf(w.z, v.z, c2);
            c3 = fmaf(w.w, v.w, c3);
        }
        float acc = (c0 + c1) + (c2 + c3);
        acc += __shfl_xor(acc, 1);
        acc += __shfl_xor(acc, 2);
        if (q == 0) out[(size_t)b * 10 + n] = sigmoidf_(acc + b3[n]);
    }
}

extern "C" void kernel_launch(void* const* d_in, const int* in_sizes, int n_in,
                              void* d_out, int out_size, void* d_ws, size_t ws_size,
                              hipStream_t stream) {
    const float* x  = (const float*)d_in[0];
    const float* sw = (const float*)d_in[1];
    const float* sa = (const float*)d_in[2];
    const float* W1 = (const float*)d_in[3];
    const float* b1 = (const float*)d_in[4];
    const float* W2 = (const float*)d_in[5];
    const float* b2 = (const float*)d_in[6];
    const float* W3 = (const float*)d_in[7];
    const float* b3 = (const float*)d_in[8];
    float* out = (float*)d_out;

    smorph_net_kernel<<<NB, 512, 0, stream>>>(x, sw, sa, W1, b1, W2, b2, W3, b3, out);
}

// Round 18
// 102.826 us; speedup vs baseline: 3.2457x; 1.1079x over previous
//
#include <hip/hip_runtime.h>

#define HW 28
#define NPIX 784
#define NB 512
#define PADW2 34                 // row stride in PIXELS (cols -3..30); 136 B, 8B-aligned rows
#define PADH 34                  // rows -3..30
#define IMG_U (PADH * PADW2)     // 1156 packed pixels = 4624 B per branch buffer

// ---------------------------------------------------------------------------
// 7x2 output tile per thread. Image pixels packed fp16x2 (ev lo, pv hi) in
// one uint; weights packed fp16x2 (qw=w*ew lo, ew hi) in one uint (49 VGPRs).
// Per tap-output:
//   num += v_dot2_f32_f16(tap, wq)        ( = ev*qw + pv*ew, FULL-rate )
//   den += v_fma_mix_f32(wq.hi, tap.lo)   ( = ew*ev, half-rate )
// r17 lesson: fma_mix is half-rate; 3 fma_mix/tap-output = 12 cyc. This is
// 6 cyc/tap-output -> ~2x conv VALU. asm keeps f16 consumption inside the
// instruction (nothing for LICM to hoist -> no r14-style spill).
// ---------------------------------------------------------------------------
__device__ __forceinline__ void conv2col(const unsigned* sbuf,
                                         const unsigned* wlds,  // LDS packed, 16B-aligned
                                         int R0, int c, float o0[7], float o1[7])
{
    unsigned Wh[49];
    {
        const uint4* wp = (const uint4*)wlds;      // broadcast, conflict-free
#pragma unroll
        for (int k = 0; k < 12; ++k) {
            uint4 q = wp[k];
            Wh[4 * k + 0] = q.x; Wh[4 * k + 1] = q.y;
            Wh[4 * k + 2] = q.z; Wh[4 * k + 3] = q.w;
        }
        Wh[48] = wlds[48];
    }

    float num0[7], num1[7], den0[7], den1[7];
#pragma unroll
    for (int r = 0; r < 7; ++r) {
        num0[r] = 0.f; num1[r] = 0.f; den0[r] = 0.f; den1[r] = 0.f;
    }

#pragma unroll
    for (int rr = 0; rr < 13; ++rr) {
        const uint2* rq = (const uint2*)(sbuf + (R0 + rr) * PADW2 + 2 * c); // 8B-aligned
        uint2 a0 = rq[0], a1 = rq[1], a2 = rq[2], a3 = rq[3];
        unsigned tp[8] = {a0.x, a0.y, a1.x, a1.y, a2.x, a2.y, a3.x, a3.y};
#pragma unroll
        for (int r = 0; r < 7; ++r) {
            if (r > rr || rr - r > 6) continue;     // compile-time fold
            const int di = rr - r;
#pragma unroll
            for (int t = 0; t < 7; ++t) {
                unsigned wq = Wh[di * 7 + t];
                asm("v_dot2_f32_f16 %0, %1, %2, %0"
                    : "+v"(num0[r]) : "v"(tp[t]),     "v"(wq));
                asm("v_dot2_f32_f16 %0, %1, %2, %0"
                    : "+v"(num1[r]) : "v"(tp[t + 1]), "v"(wq));
                asm("v_fma_mix_f32 %0, %1, %2, %0 op_sel:[1,0,0] op_sel_hi:[1,1,0]"
                    : "+v"(den0[r]) : "v"(wq), "v"(tp[t]));
                asm("v_fma_mix_f32 %0, %1, %2, %0 op_sel:[1,0,0] op_sel_hi:[1,1,0]"
                    : "+v"(den1[r]) : "v"(wq), "v"(tp[t + 1]));
            }
        }
    }
#pragma unroll
    for (int r = 0; r < 7; ++r) {
        o0[r] = num0[r] * __builtin_amdgcn_rcpf(den0[r]);
        o1[r] = num1[r] * __builtin_amdgcn_rcpf(den1[r]);
    }
}

__device__ __forceinline__ float sigmoidf_(float s) {
    return __builtin_amdgcn_rcpf(1.f + __expf(-s));
}

// ---------------------------------------------------------------------------
// FULLY FUSED, 8 waves/block, ONE BRANCH PER WAVE, one block per image
// (r13/r17 structure). LDS ~40.3 KB. __launch_bounds__(512,2): 2nd arg is
// min BLOCKS per CU -> VGPR cap 128 (r12 lesson: (512,4) -> cap 64 -> 2.7 GB
// scratch spills). Live set ~95 fits.
// ---------------------------------------------------------------------------
__global__ __launch_bounds__(512, 2) void smorph_net_kernel(
    const float* __restrict__ x,       // [512,784]
    const float* __restrict__ sw,      // [8,2,49]
    const float* __restrict__ sa,      // [8,2]
    const float* __restrict__ W1, const float* __restrict__ b1,
    const float* __restrict__ W2, const float* __restrict__ b2,
    const float* __restrict__ W3, const float* __restrict__ b3,
    float* __restrict__ out)           // [512,10]
{
    __shared__ __align__(16) unsigned bufs[8][IMG_U];    // 36,992 B
    __shared__ __align__(16) unsigned wtab[8][2][52];    //  3,328 B

    const int b    = blockIdx.x;       // 512 blocks
    const int tid  = threadIdx.x;      // 0..511
    const int f    = tid >> 6;         // wave = branch
    const int lane = tid & 63;

    unsigned* buf = bufs[f];
    const float* src = x + (size_t)b * NPIX;

    const float a1 = sa[f * 2 + 0];
    const float a2 = sa[f * 2 + 1];

    // per-branch packed weight tables (wave-local; program order protects)
    if (lane < 49) {
        union { _Float16 h[2]; unsigned u; } p;
        float w1v = sw[(f * 2 + 0) * 49 + lane];
        float e1  = __expf(a1 * w1v);
        p.h[0] = (_Float16)(w1v * e1);          // lo = qw
        p.h[1] = (_Float16)e1;                  // hi = ew
        wtab[f][0][lane] = p.u;
        float w2v = sw[(f * 2 + 1) * 49 + lane];
        float e2  = __expf(a2 * w2v);
        p.h[0] = (_Float16)(w2v * e2);
        p.h[1] = (_Float16)e2;
        wtab[f][1][lane] = p.u;
    }

    // phase 0: buf = padded packed (ev,pv); borders (ev=1,pv=0) = 0x00003C00
    for (int idx = lane; idx < IMG_U; idx += 64) {
        int pi = idx / PADW2;
        int pj = idx - pi * PADW2;
        unsigned val = 0x00003C00u;
        if (pi >= 3 && pi < 31 && pj >= 3 && pj < 31) {
            float v = src[(pi - 3) * HW + (pj - 3)];
            float e = __expf(a1 * v);
            union { _Float16 h[2]; unsigned u; } pk;
            pk.h[0] = (_Float16)e;
            pk.h[1] = (_Float16)(v * e);
            val = pk.u;
        }
        buf[idx] = val;
    }

    const bool act = (lane < 56);
    const int s  = lane / 14;          // strip (output rows 7s..7s+6)
    const int c  = lane - s * 14;      // column pair 0..13
    const int R0 = 7 * s;
    const int j2 = 2 * c;

    float o0[7], o1[7];
    if (act) conv2col(buf, wtab[f][0], R0, c, o0, o1);

    // stage-2 packed (ev,pv) overwrite interior in place (own-wave reads done)
    if (act) {
#pragma unroll
        for (int r = 0; r < 7; ++r) {
            union { _Float16 h[2]; unsigned u; } pk;
            float e0 = __expf(a2 * o0[r]);
            pk.h[0] = (_Float16)e0; pk.h[1] = (_Float16)(o0[r] * e0);
            buf[(R0 + r + 3) * PADW2 + (j2 + 3)] = pk.u;
            float e1 = __expf(a2 * o1[r]);
            pk.h[0] = (_Float16)e1; pk.h[1] = (_Float16)(o1[r] * e1);
            buf[(R0 + r + 3) * PADW2 + (j2 + 4)] = pk.u;
        }
    }

    if (act) conv2col(buf, wtab[f][1], R0, c, o0, o1);

    // dense 28x28 f32 plane aliased over own buf (3136 B <= 4624 B)
    float* outp = (float*)buf;
    if (act) {
#pragma unroll
        for (int r = 0; r < 7; ++r) {
            outp[(R0 + r) * HW + j2]     = o0[r];
            outp[(R0 + r) * HW + j2 + 1] = o1[r];
        }
    }

    // 4x4 mean pool -> REGISTER (feat write must wait: it aliases wtab)
    float poolsum = 0.f;
    if (lane < 49) {
        int pi = lane / 7;
        int pj = lane - pi * 7;
#pragma unroll
        for (int di = 0; di < 4; ++di)
#pragma unroll
            for (int dj = 0; dj < 4; ++dj)
                poolsum += outp[(pi * 4 + di) * HW + (pj * 4 + dj)];
        poolsum *= 0.0625f;
    }
    __syncthreads();                    // all convs done; wtab now dead

    // feat/h1/h2 alias the wtab region (2,384 B needed, 3,328 available)
    float* feat = (float*)&wtab[0][0][0];
    float* h1   = feat + 392;           // offset 1568 B (16B mult)
    float* h2   = h1 + 120;             // offset 2048 B (16B mult)

    if (lane < 49) feat[f * 49 + lane] = poolsum;
    __syncthreads();

    // ---- inline MLP (4 lanes per neuron) ----
    if (tid < 480) {
        int n = tid >> 2, h = tid & 3;
        const float4* wr = (const float4*)(W1 + n * 392);
        const float4* fv = (const float4*)feat;
        float c0 = 0.f, c1 = 0.f, c2 = 0.f, c3 = 0.f;
        for (int k = h; k < 98; k += 4) {
            float4 w = wr[k];
            float4 v = fv[k];
            c0 = fmaf(w.x, v.x, c0);
            c1 = fmaf(w.y, v.y, c1);
            c2 = fmaf(w.z, v.z, c2);
            c3 = fmaf(w.w, v.w, c3);
        }
        float acc = (c0 + c1) + (c2 + c3);
        acc += __shfl_xor(acc, 1);
        acc += __shfl_xor(acc, 2);
        if (h == 0) h1[n] = sigmoidf_(acc + b1[n]);
    }
    __syncthreads();

    if (tid < 336) {
        int n = tid >> 2, h = tid & 3;
        const float4* wr = (const float4*)(W2 + n * 120);
        const float4* hv = (const float4*)h1;
        float c0 = 0.f, c1 = 0.f, c2 = 0.f, c3 = 0.f;
        for (int k = h; k < 30; k += 4) {
            float4 w = wr[k];
            float4 v = hv[k];
            c0 = fmaf(w.x, v.x, c0);
            c1 = fmaf(w.y, v.y, c1);
            c2 = fmaf(w.z, v.z, c2);
            c3 = fmaf(w.w, v.w, c3);
        }
        float acc = (c0 + c1) + (c2 + c3);
        acc += __shfl_xor(acc, 1);
        acc += __shfl_xor(acc, 2);
        if (h == 0) h2[n] = sigmoidf_(acc + b2[n]);
    }
    __syncthreads();

    if (tid < 40) {
        int n = tid >> 2, q = tid & 3;
        const float4* wr = (const float4*)(W3 + n * 84);
        const float4* hv = (const float4*)h2;
        float c0 = 0.f, c1 = 0.f, c2 = 0.f, c3 = 0.f;
        for (int k = q; k < 21; k += 4) {
            float4 w = wr[k];
            float4 v = hv[k];
            c0 = fmaf(w.x, v.x, c0);
            c1 = fmaf(w.y, v.y, c1);
            c2 = fmaf(w.z, v.z, c2);
            c3 = fmaf(w.w, v.w, c3);
        }
        float acc = (c0 + c1) + (c2 + c3);
        acc += __shfl_xor(acc, 1);
        acc += __shfl_xor(acc, 2);
        if (q == 0) out[(size_t)b * 10 + n] = sigmoidf_(acc + b3[n]);
    }
}

extern "C" void kernel_launch(void* const* d_in, const int* in_sizes, int n_in,
                              void* d_out, int out_size, void* d_ws, size_t ws_size,
                              hipStream_t stream) {
    const float* x  = (const float*)d_in[0];
    const float* sw = (const float*)d_in[1];
    const float* sa = (const float*)d_in[2];
    const float* W1 = (const float*)d_in[3];
    const float* b1 = (const float*)d_in[4];
    const float* W2 = (const float*)d_in[5];
    const float* b2 = (const float*)d_in[6];
    const float* W3 = (const float*)d_in[7];
    const float* b3 = (const float*)d_in[8];
    float* out = (float*)d_out;

    smorph_net_kernel<<<NB, 512, 0, stream>>>(x, sw, sa, W1, b1, W2, b2, W3, b3, out);
}